// Round 17
// baseline (232.939 us; speedup 1.0000x reference)
//
#include <hip/hip_runtime.h>
#include <math.h>

#define NB 8
#define NP 2048
#define GRID 256        // 256 blocks, 1/CU; batch = blk & 7 (XCD co-location)
#define THREADS 512     // 8 waves/CU
#define TOLF 1e-4f
#define EPSF 1e-12f

#define AL(p)   __hip_atomic_load((p), __ATOMIC_RELAXED, __HIP_MEMORY_SCOPE_AGENT)
#define AS(p,v) __hip_atomic_store((p), (v), __ATOMIC_RELAXED, __HIP_MEMORY_SCOPE_AGENT)

// identical fmaf structure everywhere => bit-identical transformed points
__device__ inline float3 xform_pt(const float* __restrict__ T,
                                  float x, float y, float z) {
    float3 r;
    r.x = fmaf(T[0], x, fmaf(T[1], y, fmaf(T[2], z, T[9])));
    r.y = fmaf(T[3], x, fmaf(T[4], y, fmaf(T[5], z, T[10])));
    r.z = fmaf(T[6], x, fmaf(T[7], y, fmaf(T[8], z, T[11])));
    return r;
}

// ---- 3x3 Kabsch: fp64 sums/H/det/compose, fp32 Jacobi SVD ----
__device__ void kabsch3x3(const double Spq[9], const double Sp[3], const double Sq[3],
                          double R[9], double t[3]) {
    const double invN = 1.0 / (double)NP;
    double cs[3], ct[3];
#pragma unroll
    for (int i = 0; i < 3; ++i) { cs[i] = Sp[i] * invN; ct[i] = Sq[i] * invN; }
    double Hd[9];
#pragma unroll
    for (int i = 0; i < 3; ++i)
#pragma unroll
        for (int j = 0; j < 3; ++j)
            Hd[i * 3 + j] = Spq[i * 3 + j] - (double)NP * cs[i] * ct[j];

    float Bc[3][3], V[3][3];
#pragma unroll
    for (int j = 0; j < 3; ++j)
#pragma unroll
        for (int i = 0; i < 3; ++i) {
            Bc[j][i] = (float)Hd[i * 3 + j];
            V[j][i]  = (i == j) ? 1.0f : 0.0f;
        }
    for (int sweep = 0; sweep < 12; ++sweep) {
        bool rotated = false;
        for (int p = 0; p < 2; ++p)
            for (int q = p + 1; q < 3; ++q) {
                float app = 0.f, aqq = 0.f, apq = 0.f;
#pragma unroll
                for (int i = 0; i < 3; ++i) {
                    app = fmaf(Bc[p][i], Bc[p][i], app);
                    aqq = fmaf(Bc[q][i], Bc[q][i], aqq);
                    apq = fmaf(Bc[p][i], Bc[q][i], apq);
                }
                if (apq * apq > 1e-24f + 1e-12f * app * aqq) {
                    rotated = true;
                    float tau = (aqq - app) / (2.0f * apq);
                    float tt  = (tau >= 0.f ? 1.0f : -1.0f) /
                                (fabsf(tau) + sqrtf(fmaf(tau, tau, 1.0f)));
                    float c   = 1.0f / sqrtf(fmaf(tt, tt, 1.0f));
                    float sn  = c * tt;
#pragma unroll
                    for (int i = 0; i < 3; ++i) {
                        float bp = Bc[p][i], bq = Bc[q][i];
                        Bc[p][i] = c * bp - sn * bq;
                        Bc[q][i] = sn * bp + c * bq;
                        float vp = V[p][i], vq = V[q][i];
                        V[p][i] = c * vp - sn * vq;
                        V[q][i] = sn * vp + c * vq;
                    }
                }
            }
        if (!rotated) break;
    }
    float sv[3], U[3][3];
#pragma unroll
    for (int j = 0; j < 3; ++j) {
        sv[j] = sqrtf(Bc[j][0] * Bc[j][0] + Bc[j][1] * Bc[j][1] + Bc[j][2] * Bc[j][2]);
        float inv = sv[j] > 0.f ? 1.0f / sv[j] : 0.f;
#pragma unroll
        for (int i = 0; i < 3; ++i) U[j][i] = Bc[j][i] * inv;
    }
    double detH = Hd[0] * (Hd[4] * Hd[8] - Hd[5] * Hd[7])
                - Hd[1] * (Hd[3] * Hd[8] - Hd[5] * Hd[6])
                + Hd[2] * (Hd[3] * Hd[7] - Hd[4] * Hd[6]);
    float d = (detH >= 0.0) ? 1.0f : -1.0f;
    int o[3] = {0, 1, 2};
    if (sv[o[0]] < sv[o[1]]) { int tmp = o[0]; o[0] = o[1]; o[1] = tmp; }
    if (sv[o[0]] < sv[o[2]]) { int tmp = o[0]; o[0] = o[2]; o[2] = tmp; }
    if (sv[o[1]] < sv[o[2]]) { int tmp = o[1]; o[1] = o[2]; o[2] = tmp; }
    float sg[3] = {1.0f, 1.0f, d};
#pragma unroll
    for (int i = 0; i < 3; ++i)
#pragma unroll
        for (int j = 0; j < 3; ++j) {
            float acc = 0.0f;
#pragma unroll
            for (int k = 0; k < 3; ++k) acc += sg[k] * V[o[k]][i] * U[o[k]][j];
            R[i * 3 + j] = (double)acc;
        }
#pragma unroll
    for (int i = 0; i < 3; ++i)
        t[i] = ct[i] - (R[i * 3 + 0] * cs[0] + R[i * 3 + 1] * cs[1] + R[i * 3 + 2] * cs[2]);
}

// ---------------- init: reset barrier flags ----------------
__global__ __launch_bounds__(256) void icp_init(unsigned* __restrict__ flags) {
    flags[threadIdx.x] = 0u;
}

// ---------------- main: 2 barriers/iter, per-wave replicated tail ----------
// grid: 256 blocks x 512 threads; batch = blk & 7; logical id = b*32+sc.
// thread = (w = tid>>6: 8 srcs, slice = tid&63: 32 targets). Tc in REGISTERS:
// every wave polls + reduces + Kabsch's redundantly (bit-identical), lane 0
// broadcasts via __shfl. No ps staging, no tail barrier, no TcL-copy barrier.
__global__ __launch_bounds__(THREADS, 1) void icp_main(
        const float* __restrict__ psrc, const float* __restrict__ ptgt,
        double* __restrict__ partial,    // [2][256][16] parity double-buffered
        unsigned* __restrict__ flags,    // [256] logical-id arrival (monotone it)
        double* __restrict__ Tcs,        // [8][11][12] trajectories (t=0..10)
        unsigned* __restrict__ cbits) {  // [8][16] convergence bit per iter
    __shared__ float4 tg[2112];          // targets, padded: idx = j + (j>>5)
    __shared__ float2 comb[64][66];      // [slice][src] winners
    __shared__ float2 comb2[8][66];      // stage-A merged winners

    const int tid   = threadIdx.x;
    const int blk   = blockIdx.x;
    const int b     = blk & 7;           // batch (XCD co-location heuristic)
    const int sc    = blk >> 3;          // src chunk
    const int lid   = b * 32 + sc;       // logical block id (flags/partials)
    const int slice = tid & 63;          // target slice (32 targets)
    const int w     = tid >> 6;          // wave id = src group (8 pts)
    const int lane  = tid & 63;

    // per-thread transform state (identical across all threads of a block)
    float  TcL[12];
    double TcA[12];
    float  errL = 0.0f;                  // lane 0 of each wave uses it
#pragma unroll
    for (int k = 0; k < 12; ++k) {
        float idv = (k == 0 || k == 4 || k == 8) ? 1.0f : 0.0f;
        TcL[k] = idv;
        TcA[k] = (double)idv;
    }

    // stage all 2048 targets once
    const float* tb = ptgt + b * NP * 3;
    for (int j = tid; j < NP; j += THREADS) {
        float tx = tb[3 * j + 0], ty = tb[3 * j + 1], tz = tb[3 * j + 2];
        tg[j + (j >> 5)] = make_float4(tx, ty, tz,
                                       0.5f * (tx * tx + ty * ty + tz * tz));
    }
    if (sc == 0 && tid < 12) {
        float idv = (tid == 0 || tid == 4 || tid == 8) ? 1.0f : 0.0f;
        AS(&Tcs[(b * 11 + 0) * 12 + tid], (double)idv);   // Tc(0) = I
    }
    __syncthreads();

    const float* sp = psrc + (b * NP + sc * 64) * 3;   // this block's 64 srcs

    for (int it = 1; it <= 10; ++it) {
        // ---- NN: transform own 8 srcs in registers, scan 32 targets ----
        float sx[8], sy[8], sz[8], sm[8];
        int jm[8];
#pragma unroll
        for (int k = 0; k < 8; ++k) {
            const float* pp = sp + (w * 8 + k) * 3;
            float3 P = xform_pt(TcL, pp[0], pp[1], pp[2]);
            sx[k] = P.x; sy[k] = P.y; sz[k] = P.z;
            sm[k] = INFINITY; jm[k] = 0;
        }
        const int base = slice * 33, jbase = slice * 32;
#pragma unroll 4
        for (int i = 0; i < 32; ++i) {
            float4 t = tg[base + i];
            int j = jbase + i;
#pragma unroll
            for (int k = 0; k < 8; ++k) {
                float s = fmaf(-sx[k], t.x, fmaf(-sy[k], t.y, fmaf(-sz[k], t.z, t.w)));
                if (s < sm[k]) { sm[k] = s; jm[k] = j; }   // ascending j: first-min
            }
        }
#pragma unroll
        for (int k = 0; k < 8; ++k)
            comb[slice][w * 8 + k] = make_float2(sm[k], __int_as_float(jm[k]));
        __syncthreads();                                   // S1

        // ---- stage A: wave w merges its 8 slices (ascending order) ----
        {
            float fb = INFINITY; int fj = 0;
#pragma unroll
            for (int q = 0; q < 8; ++q) {
                float2 e = comb[w * 8 + q][lane];
                if (e.x < fb) { fb = e.x; fj = __float_as_int(e.y); }
            }
            comb2[w][lane] = make_float2(fb, __int_as_float(fj));
        }
        __syncthreads();                                   // S2

        double* pbase = partial + (size_t)(it & 1) * GRID * 16;

        // ---- wave 0: final merge + fp64 sums + publish ----
        if (w == 0) {
            float fb = INFINITY; int fj = 0;
#pragma unroll
            for (int q = 0; q < 8; ++q) {                  // ascending: first-min
                float2 e = comb2[q][lane];
                if (e.x < fb) { fb = e.x; fj = __float_as_int(e.y); }
            }
            const float* pp = sp + lane * 3;
            float3 P = xform_pt(TcL, pp[0], pp[1], pp[2]); // bit-identical recompute
            float Pw = P.x * P.x + P.y * P.y + P.z * P.z;
            float d2 = fmaf(2.0f, fb, Pw);
            float dist = sqrtf(fmaxf(d2, EPSF));
            float4 Q = tg[fj + (fj >> 5)];

            double v[16];
            v[0] = dist;
            v[1] = P.x; v[2] = P.y; v[3] = P.z;
            v[4] = Q.x; v[5] = Q.y; v[6] = Q.z;
            v[7]  = (double)P.x * Q.x; v[8]  = (double)P.x * Q.y; v[9]  = (double)P.x * Q.z;
            v[10] = (double)P.y * Q.x; v[11] = (double)P.y * Q.y; v[12] = (double)P.y * Q.z;
            v[13] = (double)P.z * Q.x; v[14] = (double)P.z * Q.y; v[15] = (double)P.z * Q.z;
#pragma unroll
            for (int k = 0; k < 16; ++k) {
                double x = v[k];
#pragma unroll
                for (int off = 32; off > 0; off >>= 1) x += __shfl_down(x, off);
                v[k] = x;
            }
            if (lane == 0) {
                double* dst = pbase + lid * 16;
#pragma unroll
                for (int k = 0; k < 16; ++k) AS(dst + k, v[k]);
                asm volatile("s_waitcnt vmcnt(0)" ::: "memory");
                AS(&flags[lid], (unsigned)it);
            }
        }

        // ---- EVERY wave: poll batch flags, reduce partials, Kabsch, bcast ----
        {
            bool ok;
            do {
                ok = (lane < 32) ? (AL(&flags[b * 32 + lane]) >= (unsigned)it) : true;
                if (!__all(ok)) __builtin_amdgcn_s_sleep(1); else break;
            } while (true);
        }
        {
            double acc[16];
            if (lane < 32) {
                const double* pp2 = pbase + (b * 32 + lane) * 16;
#pragma unroll
                for (int k = 0; k < 16; ++k) acc[k] = AL(pp2 + k);
#pragma unroll
                for (int k = 0; k < 16; ++k) {
                    double x = acc[k];
                    x += __shfl_down(x, 16);
                    x += __shfl_down(x, 8);
                    x += __shfl_down(x, 4);
                    x += __shfl_down(x, 2);
                    x += __shfl_down(x, 1);
                    acc[k] = x;
                }
                if (lane == 0) {
                    float errnew = (float)(acc[0] * (1.0 / (double)NP));
                    unsigned cb = (fabsf(errnew - errL) < TOLF) ? 1u : 0u;
                    errL = errnew;
                    double R[9], t[3];
                    kabsch3x3(&acc[7], &acc[1], &acc[4], R, t);
                    double To[12];
#pragma unroll
                    for (int k = 0; k < 12; ++k) To[k] = TcA[k];
#pragma unroll
                    for (int i = 0; i < 3; ++i) {
#pragma unroll
                        for (int j = 0; j < 3; ++j)
                            TcA[i * 3 + j] = R[i * 3 + 0] * To[0 + j]
                                           + R[i * 3 + 1] * To[3 + j]
                                           + R[i * 3 + 2] * To[6 + j];
                        TcA[9 + i] = R[i * 3 + 0] * To[9] + R[i * 3 + 1] * To[10]
                                   + R[i * 3 + 2] * To[11] + t[i];
                    }
                    if (sc == 0 && w == 0) {
#pragma unroll
                        for (int k = 0; k < 12; ++k)
                            AS(&Tcs[(b * 11 + it) * 12 + k], TcA[k]);
                        AS(&cbits[b * 16 + it], cb);
                    }
                }
            }
            // broadcast composed Tc from lane 0 of this wave to all 64 lanes
#pragma unroll
            for (int k = 0; k < 12; ++k) {
                double nv = __shfl(TcA[k], 0);
                TcA[k] = nv;
                TcL[k] = (float)nv;
            }
        }
        // next iteration's S1 fences all cross-wave LDS hazards
    }
}

// ---------------- resolver: find freeze step k*, emit Tc(k*-1) ----------------
__global__ __launch_bounds__(64) void icp_resolve(const double* __restrict__ Tcs,
                                                  const unsigned* __restrict__ cbits,
                                                  float* __restrict__ out) {
    __shared__ int ksel;
    int tid = threadIdx.x;
    if (tid == 0) {
        int sel = 10;
        for (int t = 1; t <= 10; ++t) {
            bool all = true;
            for (int b2 = 0; b2 < NB; ++b2) all = all && (cbits[b2 * 16 + t] != 0u);
            if (all) { sel = t - 1; break; }
        }
        ksel = sel;
    }
    __syncthreads();
    if (tid < NB) {
        const double* T = Tcs + ((size_t)tid * 11 + ksel) * 12;
        float* o = out + tid * 12;
#pragma unroll
        for (int i = 0; i < 3; ++i) {
#pragma unroll
            for (int j = 0; j < 3; ++j) o[i * 4 + j] = (float)T[i * 3 + j];
            o[i * 4 + 3] = (float)T[9 + i];
        }
    }
}

extern "C" void kernel_launch(void* const* d_in, const int* in_sizes, int n_in,
                              void* d_out, int out_size, void* d_ws, size_t ws_size,
                              hipStream_t stream) {
    const float* psrc = (const float*)d_in[0];
    const float* ptgt = (const float*)d_in[1];
    float* out = (float*)d_out;

    char* ws = (char*)d_ws;
    size_t off = 0;
    double* partial = (double*)(ws + off); off += 2ull * GRID * 16 * sizeof(double);
    unsigned* flags = (unsigned*)(ws + off); off += GRID * sizeof(unsigned);
    double* Tcs   = (double*)(ws + off);   off += (size_t)NB * 11 * 12 * sizeof(double);
    unsigned* cbits = (unsigned*)(ws + off); off += NB * 16 * sizeof(unsigned);

    icp_init<<<1, 256, 0, stream>>>(flags);
    icp_main<<<GRID, THREADS, 0, stream>>>(psrc, ptgt, partial, flags, Tcs, cbits);
    icp_resolve<<<1, 64, 0, stream>>>(Tcs, cbits, out);
}

// Round 18
// 180.191 us; speedup vs baseline: 1.2927x; 1.2927x over previous
//
#include <hip/hip_runtime.h>
#include <math.h>

#define NB 8
#define NP 2048
#define GRID 256        // 256 blocks, 1/CU; batch = blk & 7 (XCD co-location)
#define THREADS 512     // 8 waves/CU
#define TOLF 1e-4f
#define EPSF 1e-12f

#define AL(p)   __hip_atomic_load((p), __ATOMIC_RELAXED, __HIP_MEMORY_SCOPE_AGENT)
#define AS(p,v) __hip_atomic_store((p), (v), __ATOMIC_RELAXED, __HIP_MEMORY_SCOPE_AGENT)

// identical fmaf structure everywhere => bit-identical transformed points
__device__ inline float3 xform_pt(const float* __restrict__ T,
                                  float x, float y, float z) {
    float3 r;
    r.x = fmaf(T[0], x, fmaf(T[1], y, fmaf(T[2], z, T[9])));
    r.y = fmaf(T[3], x, fmaf(T[4], y, fmaf(T[5], z, T[10])));
    r.z = fmaf(T[6], x, fmaf(T[7], y, fmaf(T[8], z, T[11])));
    return r;
}

// ---- 3x3 Kabsch: fp64 sums/H/det/compose, fp32 Jacobi SVD ----
__device__ void kabsch3x3(const double Spq[9], const double Sp[3], const double Sq[3],
                          double R[9], double t[3]) {
    const double invN = 1.0 / (double)NP;
    double cs[3], ct[3];
#pragma unroll
    for (int i = 0; i < 3; ++i) { cs[i] = Sp[i] * invN; ct[i] = Sq[i] * invN; }
    double Hd[9];
#pragma unroll
    for (int i = 0; i < 3; ++i)
#pragma unroll
        for (int j = 0; j < 3; ++j)
            Hd[i * 3 + j] = Spq[i * 3 + j] - (double)NP * cs[i] * ct[j];

    float Bc[3][3], V[3][3];
#pragma unroll
    for (int j = 0; j < 3; ++j)
#pragma unroll
        for (int i = 0; i < 3; ++i) {
            Bc[j][i] = (float)Hd[i * 3 + j];
            V[j][i]  = (i == j) ? 1.0f : 0.0f;
        }
    for (int sweep = 0; sweep < 12; ++sweep) {
        bool rotated = false;
        for (int p = 0; p < 2; ++p)
            for (int q = p + 1; q < 3; ++q) {
                float app = 0.f, aqq = 0.f, apq = 0.f;
#pragma unroll
                for (int i = 0; i < 3; ++i) {
                    app = fmaf(Bc[p][i], Bc[p][i], app);
                    aqq = fmaf(Bc[q][i], Bc[q][i], aqq);
                    apq = fmaf(Bc[p][i], Bc[q][i], apq);
                }
                if (apq * apq > 1e-24f + 1e-12f * app * aqq) {
                    rotated = true;
                    float tau = (aqq - app) / (2.0f * apq);
                    float tt  = (tau >= 0.f ? 1.0f : -1.0f) /
                                (fabsf(tau) + sqrtf(fmaf(tau, tau, 1.0f)));
                    float c   = 1.0f / sqrtf(fmaf(tt, tt, 1.0f));
                    float sn  = c * tt;
#pragma unroll
                    for (int i = 0; i < 3; ++i) {
                        float bp = Bc[p][i], bq = Bc[q][i];
                        Bc[p][i] = c * bp - sn * bq;
                        Bc[q][i] = sn * bp + c * bq;
                        float vp = V[p][i], vq = V[q][i];
                        V[p][i] = c * vp - sn * vq;
                        V[q][i] = sn * vp + c * vq;
                    }
                }
            }
        if (!rotated) break;
    }
    float sv[3], U[3][3];
#pragma unroll
    for (int j = 0; j < 3; ++j) {
        sv[j] = sqrtf(Bc[j][0] * Bc[j][0] + Bc[j][1] * Bc[j][1] + Bc[j][2] * Bc[j][2]);
        float inv = sv[j] > 0.f ? 1.0f / sv[j] : 0.f;
#pragma unroll
        for (int i = 0; i < 3; ++i) U[j][i] = Bc[j][i] * inv;
    }
    double detH = Hd[0] * (Hd[4] * Hd[8] - Hd[5] * Hd[7])
                - Hd[1] * (Hd[3] * Hd[8] - Hd[5] * Hd[6])
                + Hd[2] * (Hd[3] * Hd[7] - Hd[4] * Hd[6]);
    float d = (detH >= 0.0) ? 1.0f : -1.0f;
    int o[3] = {0, 1, 2};
    if (sv[o[0]] < sv[o[1]]) { int tmp = o[0]; o[0] = o[1]; o[1] = tmp; }
    if (sv[o[0]] < sv[o[2]]) { int tmp = o[0]; o[0] = o[2]; o[2] = tmp; }
    if (sv[o[1]] < sv[o[2]]) { int tmp = o[1]; o[1] = o[2]; o[2] = tmp; }
    float sg[3] = {1.0f, 1.0f, d};
#pragma unroll
    for (int i = 0; i < 3; ++i)
#pragma unroll
        for (int j = 0; j < 3; ++j) {
            float acc = 0.0f;
#pragma unroll
            for (int k = 0; k < 3; ++k) acc += sg[k] * V[o[k]][i] * U[o[k]][j];
            R[i * 3 + j] = (double)acc;
        }
#pragma unroll
    for (int i = 0; i < 3; ++i)
        t[i] = ct[i] - (R[i * 3 + 0] * cs[0] + R[i * 3 + 1] * cs[1] + R[i * 3 + 2] * cs[2]);
}

// ---------------- init: reset barrier flags ----------------
__global__ __launch_bounds__(256) void icp_init(unsigned* __restrict__ flags) {
    flags[threadIdx.x] = 0u;
}

// ---------------- main: 8 independent batches, per-batch 32-block barrier ----
// batch = blk & 7 (XCD co-location heuristic). Logical block id = b*32+sc.
// thread = (g = tid>>7: 16 srcs, slice = tid&127: 16 targets) — each
// ds_read_b128 feeds 16 srcs (~192 issue-cycles, covers LDS latency).
__global__ __launch_bounds__(THREADS, 1) void icp_main(
        const float* __restrict__ psrc, const float* __restrict__ ptgt,
        double* __restrict__ partial,    // [2][256][16] parity double-buffered
        unsigned* __restrict__ flags,    // [256] logical-id arrival (monotone it)
        double* __restrict__ Tcs,        // [8][11][12] trajectories (t=0..10)
        unsigned* __restrict__ cbits) {  // [8][16] convergence bit per iter
    __shared__ float4 tg[2112];          // targets, padded: idx = j + (j>>5)
    __shared__ float4 ps[64];            // transformed src pts (x,y,z,|P|^2)
    __shared__ float2 comb[128][66];     // [slice][src] winners
    __shared__ float2 comb2[8][66];      // stage-A merged winners
    __shared__ float  TcL[12];
    __shared__ double TcA[12];

    const int tid   = threadIdx.x;
    const int blk   = blockIdx.x;
    const int b     = blk & 7;           // batch == XCD (if round-robin dispatch)
    const int sc    = blk >> 3;          // src chunk
    const int lid   = b * 32 + sc;       // logical block id (flags/partials)
    const int slice = tid & 127;         // target slice (16 targets)
    const int g     = tid >> 7;          // src group (16 pts)
    const int w     = tid >> 6;          // wave id (stage-A merge)

    float errL = 0.0f;

    // stage all 2048 targets once (float4, padded)
    const float* tb = ptgt + b * NP * 3;
    for (int j = tid; j < NP; j += THREADS) {
        float tx = tb[3 * j + 0], ty = tb[3 * j + 1], tz = tb[3 * j + 2];
        tg[j + (j >> 5)] = make_float4(tx, ty, tz,
                                       0.5f * (tx * tx + ty * ty + tz * tz));
    }
    if (tid < 12) {
        float idv = (tid == 0 || tid == 4 || tid == 8) ? 1.0f : 0.0f;
        TcL[tid] = idv;
        TcA[tid] = (double)idv;
        if (sc == 0) AS(&Tcs[(b * 11 + 0) * 12 + tid], (double)idv);
    }
    __syncthreads();

    for (int it = 1; it <= 10; ++it) {
        // ---- transform this chunk's 64 src points with current TcL ----
        if (tid < 64) {
            const float* pp = psrc + (b * NP + sc * 64 + tid) * 3;
            float3 P = xform_pt(TcL, pp[0], pp[1], pp[2]);
            ps[tid] = make_float4(P.x, P.y, P.z,
                                  P.x * P.x + P.y * P.y + P.z * P.z);
        }
        __syncthreads();

        // ---- NN: 16 src pts/thread x 16 targets of this slice ----
        float sx[16], sy[16], sz[16], sm[16];
        int jm[16];
#pragma unroll
        for (int k = 0; k < 16; ++k) {
            float4 P = ps[g * 16 + k];
            sx[k] = P.x; sy[k] = P.y; sz[k] = P.z;
            sm[k] = INFINITY; jm[k] = 0;
        }
        const int jbase = slice * 16;
        const int base  = jbase + (slice >> 1);   // tg idx of target jbase
#pragma unroll 2
        for (int i = 0; i < 16; ++i) {
            float4 t = tg[base + i];
            int j = jbase + i;
#pragma unroll
            for (int k = 0; k < 16; ++k) {
                float s = fmaf(-sx[k], t.x, fmaf(-sy[k], t.y, fmaf(-sz[k], t.z, t.w)));
                if (s < sm[k]) { sm[k] = s; jm[k] = j; }   // ascending j: first-min
            }
        }
#pragma unroll
        for (int k = 0; k < 16; ++k)
            comb[slice][g * 16 + k] = make_float2(sm[k], __int_as_float(jm[k]));
        __syncthreads();

        // ---- stage A: each wave merges its 16 slices (ascending order) ----
        {
            int l = tid & 63;
            float fb = INFINITY; int fj = 0;
#pragma unroll
            for (int q = 0; q < 16; ++q) {
                float2 e = comb[w * 16 + q][l];
                if (e.x < fb) { fb = e.x; fj = __float_as_int(e.y); }
            }
            comb2[w][l] = make_float2(fb, __int_as_float(fj));
        }
        __syncthreads();

        double* pbase = partial + (size_t)(it & 1) * GRID * 16;

        // ---- wave 0: final merge + fp64 sums + publish; wave 1: poll ----
        if (tid < 64) {
            float fb = INFINITY; int fj = 0;
#pragma unroll
            for (int q = 0; q < 8; ++q) {            // ascending: first-min
                float2 e = comb2[q][tid];
                if (e.x < fb) { fb = e.x; fj = __float_as_int(e.y); }
            }
            float4 P = ps[tid];
            float d2 = fmaf(2.0f, fb, P.w);
            float dist = sqrtf(fmaxf(d2, EPSF));
            float4 Q = tg[fj + (fj >> 5)];

            double v[16];
            v[0] = dist;
            v[1] = P.x; v[2] = P.y; v[3] = P.z;
            v[4] = Q.x; v[5] = Q.y; v[6] = Q.z;
            v[7]  = (double)P.x * Q.x; v[8]  = (double)P.x * Q.y; v[9]  = (double)P.x * Q.z;
            v[10] = (double)P.y * Q.x; v[11] = (double)P.y * Q.y; v[12] = (double)P.y * Q.z;
            v[13] = (double)P.z * Q.x; v[14] = (double)P.z * Q.y; v[15] = (double)P.z * Q.z;
#pragma unroll
            for (int k = 0; k < 16; ++k) {
                double x = v[k];
#pragma unroll
                for (int off = 32; off > 0; off >>= 1) x += __shfl_down(x, off);
                v[k] = x;
            }
            if (tid == 0) {
                double* dst = pbase + lid * 16;
#pragma unroll
                for (int k = 0; k < 16; ++k) AS(dst + k, v[k]);
                asm volatile("s_waitcnt vmcnt(0)" ::: "memory");
                AS(&flags[lid], (unsigned)it);
            }
        } else if (tid < 128) {
            int l = tid - 64;
            bool ok;
            do {
                ok = (l < 32) ? (AL(&flags[b * 32 + l]) >= (unsigned)it) : true;
                if (!__all(ok)) __builtin_amdgcn_s_sleep(1); else break;
            } while (true);
        }
        __syncthreads();

        // ---- lanes 0-31: read batch partials + fixed-order reduce + Kabsch ----
        if (tid < 32) {
            double acc[16];
            const double* pp2 = pbase + (b * 32 + tid) * 16;
#pragma unroll
            for (int k = 0; k < 16; ++k) acc[k] = AL(pp2 + k);
#pragma unroll
            for (int k = 0; k < 16; ++k) {
                double x = acc[k];
                x += __shfl_down(x, 16);
                x += __shfl_down(x, 8);
                x += __shfl_down(x, 4);
                x += __shfl_down(x, 2);
                x += __shfl_down(x, 1);
                acc[k] = x;
            }
            if (tid == 0) {
                float errnew = (float)(acc[0] * (1.0 / (double)NP));
                unsigned cb = (fabsf(errnew - errL) < TOLF) ? 1u : 0u;
                errL = errnew;
                double R[9], t[3];
                kabsch3x3(&acc[7], &acc[1], &acc[4], R, t);
                double To[12];
#pragma unroll
                for (int k = 0; k < 12; ++k) To[k] = TcA[k];
#pragma unroll
                for (int i = 0; i < 3; ++i) {
#pragma unroll
                    for (int j = 0; j < 3; ++j)
                        TcA[i * 3 + j] = R[i * 3 + 0] * To[0 + j]
                                       + R[i * 3 + 1] * To[3 + j]
                                       + R[i * 3 + 2] * To[6 + j];
                    TcA[9 + i] = R[i * 3 + 0] * To[9] + R[i * 3 + 1] * To[10]
                               + R[i * 3 + 2] * To[11] + t[i];
                }
                if (sc == 0) {
#pragma unroll
                    for (int k = 0; k < 12; ++k)
                        AS(&Tcs[(b * 11 + it) * 12 + k], TcA[k]);
                    AS(&cbits[b * 16 + it], cb);
                }
            }
        }
        __syncthreads();
        if (tid < 12) TcL[tid] = (float)TcA[tid];
        __syncthreads();
    }
}

// ---------------- resolver: find freeze step k*, emit Tc(k*-1) ----------------
__global__ __launch_bounds__(64) void icp_resolve(const double* __restrict__ Tcs,
                                                  const unsigned* __restrict__ cbits,
                                                  float* __restrict__ out) {
    __shared__ int ksel;
    int tid = threadIdx.x;
    if (tid == 0) {
        int sel = 10;
        for (int t = 1; t <= 10; ++t) {
            bool all = true;
            for (int b2 = 0; b2 < NB; ++b2) all = all && (cbits[b2 * 16 + t] != 0u);
            if (all) { sel = t - 1; break; }
        }
        ksel = sel;
    }
    __syncthreads();
    if (tid < NB) {
        const double* T = Tcs + ((size_t)tid * 11 + ksel) * 12;
        float* o = out + tid * 12;
#pragma unroll
        for (int i = 0; i < 3; ++i) {
#pragma unroll
            for (int j = 0; j < 3; ++j) o[i * 4 + j] = (float)T[i * 3 + j];
            o[i * 4 + 3] = (float)T[9 + i];
        }
    }
}

extern "C" void kernel_launch(void* const* d_in, const int* in_sizes, int n_in,
                              void* d_out, int out_size, void* d_ws, size_t ws_size,
                              hipStream_t stream) {
    const float* psrc = (const float*)d_in[0];
    const float* ptgt = (const float*)d_in[1];
    float* out = (float*)d_out;

    char* ws = (char*)d_ws;
    size_t off = 0;
    double* partial = (double*)(ws + off); off += 2ull * GRID * 16 * sizeof(double);
    unsigned* flags = (unsigned*)(ws + off); off += GRID * sizeof(unsigned);
    double* Tcs   = (double*)(ws + off);   off += (size_t)NB * 11 * 12 * sizeof(double);
    unsigned* cbits = (unsigned*)(ws + off); off += NB * 16 * sizeof(unsigned);

    icp_init<<<1, 256, 0, stream>>>(flags);
    icp_main<<<GRID, THREADS, 0, stream>>>(psrc, ptgt, partial, flags, Tcs, cbits);
    icp_resolve<<<1, 64, 0, stream>>>(Tcs, cbits, out);
}